// Round 14
// baseline (70.045 us; speedup 1.0000x reference)
//
#include <hip/hip_runtime.h>

#define CIN  32
#define OCH  64
#define HH   56
#define WW   56
#define BB   4
#define OT   4                  // output channels per block
#define IMG  (HH * WW)          // 3136
#define NW   18432              // 64*32*3*3
#define PH   58
#define PW   58
#define PIMG (PH * PW)          // 3364 padded image
#define NXPK (BB * (CIN/2) * PIMG)   // 215296 packed x uints
#define XPKBLKS (NXPK / 256)         // 841 (exact)
#define NWPK (OCH * (CIN/2) * 9)     // 9216 packed weight uints
#define WPKBLKS (NWPK / 256)         // 36 (exact)
#define WOFFu 64                     // packed weights at wsu+64 (uint units)
#define XOFFu (WOFFu + NWPK)         // 9280: packed x follows (256B aligned)

typedef _Float16 h2 __attribute__((ext_vector_type(2)));

// v_pk_min_f16, both operands VGPR (weights come from LDS uint4).
static __device__ __forceinline__ h2 pkmin_vv(h2 xv, unsigned wu) {
    unsigned xu = __builtin_bit_cast(unsigned, xv);
    unsigned ru;
    asm("v_pk_min_f16 %0, %1, %2" : "=v"(ru) : "v"(xu), "v"(wu));
    return __builtin_bit_cast(h2, ru);
}

// One dispatch, three jobs (fp16 channel-pair packing):
//   blocks [0,841)    : zero-padded x -> fp16 pairs (ch 2cp, 2cp+1) at wsu+XOFFu
//   blocks [841,877)  : weights -> fp16 pairs at wsu+WOFFu, ordered
//                       [otile][wv][cl][t][oo]: each ds_read_b128 in minconv
//                       delivers tap t of channel-pair cl for ALL 4 oo.
//   block  877        : mu = mean|w| (fp32) -> ws[0]
__global__ __launch_bounds__(256) void prep(const float* __restrict__ x,
                                            const float* __restrict__ w,
                                            float* __restrict__ ws) {
    unsigned* wsu = reinterpret_cast<unsigned*>(ws);
    if (blockIdx.x < XPKBLKS) {
        int idx = blockIdx.x * 256 + threadIdx.x;      // 0..NXPK-1
        int bc  = idx / PIMG;                          // b*16 + cp
        int r   = idx - bc * PIMG;
        int ph  = r / PW;
        int pw  = r - ph * PW;
        int hh  = ph - 1, wc = pw - 1;
        float v0 = 0.f, v1 = 0.f;
        if ((unsigned)hh < (unsigned)HH && (unsigned)wc < (unsigned)WW) {
            int base = ((bc >> 4) * CIN + (bc & 15) * 2) * IMG + hh * WW + wc;
            v0 = x[base];                              // channel 2cp   (coalesced)
            v1 = x[base + IMG];                        // channel 2cp+1
        }
        h2 p; p.x = (_Float16)v0; p.y = (_Float16)v1;
        wsu[XOFFu + idx] = __builtin_bit_cast(unsigned, p);
        return;
    }
    if (blockIdx.x < XPKBLKS + WPKBLKS) {
        int idx = (blockIdx.x - XPKBLKS) * 256 + threadIdx.x;  // 0..NWPK-1
        // decode [otile][wvq][cl][t][oo] ; strides 576/288/36/4/1
        int otile = idx / 576;
        int r     = idx - otile * 576;
        int wvq   = r / 288;
        int r2    = r - wvq * 288;
        int cl    = r2 / 36;
        int r3    = r2 - cl * 36;
        int t     = r3 >> 2;
        int oo    = r3 & 3;
        int o     = otile * OT + oo;
        int cp    = wvq * 8 + cl;
        int src   = o * (CIN * 9) + cp * 18 + t;
        h2 p; p.x = (_Float16)w[src]; p.y = (_Float16)w[src + 9];
        wsu[WOFFu + idx] = __builtin_bit_cast(unsigned, p);
        return;
    }
    // |w| mean (fp32 source) -> ws[0]
    float s = 0.f;
    const float4* w4 = reinterpret_cast<const float4*>(w);
    #pragma unroll
    for (int k = 0; k < 18; ++k) {
        float4 v = w4[k * 256 + threadIdx.x];
        s += fabsf(v.x) + fabsf(v.y) + fabsf(v.z) + fabsf(v.w);
    }
    #pragma unroll
    for (int off = 32; off; off >>= 1) s += __shfl_down(s, off);
    __shared__ float sm[4];
    if ((threadIdx.x & 63) == 0) sm[threadIdx.x >> 6] = s;
    __syncthreads();
    if (threadIdx.x == 0)
        ws[0] = (sm[0] + sm[1] + sm[2] + sm[3]) * (1.0f / (float)NW);
}

// R12 post-mortem: weight-path fixes moved <=1.4us; VGPR=56 < xall[72] proved
// the compiler REMATERIALIZES x-loads per oo (explains R7/R9 nulls). Fix:
// oo-INNER loop -- per (cp,t) one ds_read_b128 yields all 4 oo weights, the
// 9 x-taps are loaded once and consumed immediately 4x (nothing to reload).
// Batch-pairing (grid.z=2, lane does batches b and b+2): weights amortized
// 2x, 8 independent fdot2 chains, ~3 waves/SIMD with VGPR<64.
// R3 lesson: readfirstlane anything wave-uniform used in addressing.
// R2 lesson: all register-array indices compile-time.
__global__ __launch_bounds__(128) void minconv_kernel(const float* __restrict__ ws,
                                                      const float* __restrict__ wts,
                                                      float* __restrict__ out) {
    const unsigned* wsu = reinterpret_cast<const unsigned*>(ws);
    const int lane = threadIdx.x & 63;
    const int wv   = threadIdx.x >> 6;
    const int wvs  = __builtin_amdgcn_readfirstlane(wv);   // SGPR copy
    const int hw = blockIdx.x * 64 + lane;             // 0..3135 exact
    const int o0 = blockIdx.y * OT;
    const int b2 = blockIdx.z;                         // batches b2 and b2+2
    const int h  = hw / WW;
    const int w  = hw - h * WW;

    const float mu = ws[0];                            // uniform s_load

    __shared__ __align__(16) unsigned wlds[576];       // o-tile weights [wv][cl][t][oo]
    __shared__ float red[2][4][64];                    // epilogue exchange, 2 KiB

    // ---- stage weights: straight copy of 576 contiguous dwords ----
    {
        const unsigned* wt = wsu + WOFFu + blockIdx.y * 576;
        const int tid = threadIdx.x;
        *reinterpret_cast<uint4*>(&wlds[tid * 4]) =
            *reinterpret_cast<const uint4*>(&wt[tid * 4]);     // 512 dwords
        if (tid < 64) wlds[512 + tid] = wt[512 + tid];         // remaining 64
    }

    const int cp0 = wvs * 8;                           // this wave's channel-pairs
    const unsigned* xqA = wsu + XOFFu + (size_t)(b2 * 16 + cp0) * PIMG + h * PW + w;
    const unsigned* xqB = xqA + 2 * 16 * PIMG;         // batch b2+2, same pixel

    __syncthreads();                                   // weights staged

    // ---- main: cp outer, oo fused into each b128 weight read ----
    h2 ones; ones.x = (_Float16)1.f; ones.y = (_Float16)1.f;
    float aA0 = 0.f, aA1 = 0.f, aA2 = 0.f, aA3 = 0.f;  // batch b2,  oo 0..3
    float aB0 = 0.f, aB1 = 0.f, aB2 = 0.f, aB3 = 0.f;  // batch b2+2, oo 0..3
    const unsigned* wl = wlds + wv * 288;              // per-wave LDS base

    #pragma unroll
    for (int cp = 0; cp < 8; ++cp) {
        h2 xA[9], xB[9];                               // 18 regs, used immediately
        #pragma unroll
        for (int kh = 0; kh < 3; ++kh)
            #pragma unroll
            for (int kw = 0; kw < 3; ++kw) {
                xA[kh * 3 + kw] = __builtin_bit_cast(h2, xqA[cp * PIMG + kh * PW + kw]);
                xB[kh * 3 + kw] = __builtin_bit_cast(h2, xqB[cp * PIMG + kh * PW + kw]);
            }
        #pragma unroll
        for (int t = 0; t < 9; ++t) {
            uint4 q = *reinterpret_cast<const uint4*>(&wl[cp * 36 + t * 4]);
            h2 mA0 = pkmin_vv(xA[t], q.x);
            aA0 = __builtin_amdgcn_fdot2(mA0, ones, aA0, false);
            h2 mA1 = pkmin_vv(xA[t], q.y);
            aA1 = __builtin_amdgcn_fdot2(mA1, ones, aA1, false);
            h2 mA2 = pkmin_vv(xA[t], q.z);
            aA2 = __builtin_amdgcn_fdot2(mA2, ones, aA2, false);
            h2 mA3 = pkmin_vv(xA[t], q.w);
            aA3 = __builtin_amdgcn_fdot2(mA3, ones, aA3, false);
            h2 mB0 = pkmin_vv(xB[t], q.x);
            aB0 = __builtin_amdgcn_fdot2(mB0, ones, aB0, false);
            h2 mB1 = pkmin_vv(xB[t], q.y);
            aB1 = __builtin_amdgcn_fdot2(mB1, ones, aB1, false);
            h2 mB2 = pkmin_vv(xB[t], q.z);
            aB2 = __builtin_amdgcn_fdot2(mB2, ones, aB2, false);
            h2 mB3 = pkmin_vv(xB[t], q.w);
            aB3 = __builtin_amdgcn_fdot2(mB3, ones, aB3, false);
        }
    }

    // cross-wave combine: wave0 keeps batch A (b2), wave1 keeps batch B (b2+2)
    if (wv == 0) {
        red[0][0][lane] = aB0;
        red[0][1][lane] = aB1;
        red[0][2][lane] = aB2;
        red[0][3][lane] = aB3;
    } else {
        red[1][0][lane] = aA0;
        red[1][1][lane] = aA1;
        red[1][2][lane] = aA2;
        red[1][3][lane] = aA3;
    }
    __syncthreads();

    if (wv == 0) {
        float* ob = out + ((size_t)b2 * OCH + o0) * IMG + hw;
        ob[0 * IMG] = mu * (aA0 + red[1][0][lane]);
        ob[1 * IMG] = mu * (aA1 + red[1][1][lane]);
        ob[2 * IMG] = mu * (aA2 + red[1][2][lane]);
        ob[3 * IMG] = mu * (aA3 + red[1][3][lane]);
    } else {
        float* ob = out + ((size_t)(b2 + 2) * OCH + o0) * IMG + hw;
        ob[0 * IMG] = mu * (aB0 + red[0][0][lane]);
        ob[1 * IMG] = mu * (aB1 + red[0][1][lane]);
        ob[2 * IMG] = mu * (aB2 + red[0][2][lane]);
        ob[3 * IMG] = mu * (aB3 + red[0][3][lane]);
    }
}

extern "C" void kernel_launch(void* const* d_in, const int* in_sizes, int n_in,
                              void* d_out, int out_size, void* d_ws, size_t ws_size,
                              hipStream_t stream) {
    const float* x   = (const float*)d_in[0];   // 4*32*56*56
    const float* w   = (const float*)d_in[1];   // 64*32*3*3
    float*       out = (float*)d_out;           // 4*64*56*56
    float*       ws  = (float*)d_ws;

    prep<<<XPKBLKS + WPKBLKS + 1, 256, 0, stream>>>(x, w, ws);
    dim3 grid(IMG / 64, OCH / OT, BB / 2);      // 49 x 16 x 2 = 1568 blocks
    minconv_kernel<<<grid, 128, 0, stream>>>(ws, w, out);
}

// Round 15
// 68.272 us; speedup vs baseline: 1.0260x; 1.0260x over previous
//
#include <hip/hip_runtime.h>

#define CIN  32
#define OCH  64
#define HH   56
#define WW   56
#define BB   4
#define OT   4                  // output channels per block
#define IMG  (HH * WW)          // 3136
#define NW   18432              // 64*32*3*3
#define PH   58
#define PW   58
#define PIMG (PH * PW)          // 3364 padded image
#define NXPK (BB * (CIN/2) * PIMG)   // 215296 packed x uints
#define XPKBLKS (NXPK / 256)         // 841 (exact)
#define NWPK (OCH * (CIN/2) * 9)     // 9216 packed weight uints
#define WPKBLKS (NWPK / 256)         // 36 (exact)
#define WOFFu 64                     // packed weights at wsu+64 (uint units)
#define XOFFu (WOFFu + NWPK)         // 9280: packed x follows (256B aligned)

typedef _Float16 h2 __attribute__((ext_vector_type(2)));

// v_pk_min_f16 with weight as direct SGPR source (VOP3P allows 1 SGPR operand).
static __device__ __forceinline__ h2 pkmin_vs(h2 xv, unsigned wu) {
    unsigned xu = __builtin_bit_cast(unsigned, xv);
    unsigned ru;
    asm("v_pk_min_f16 %0, %1, %2" : "=v"(ru) : "v"(xu), "s"(wu));
    return __builtin_bit_cast(h2, ru);
}
// v_pk_add_f16 (full-rate packed fp16 add) -- forced via asm (R2 lesson:
// builtins on h2 may scalarize).
static __device__ __forceinline__ h2 pkadd(h2 a, h2 b) {
    unsigned au = __builtin_bit_cast(unsigned, a);
    unsigned bu = __builtin_bit_cast(unsigned, b);
    unsigned ru;
    asm("v_pk_add_f16 %0, %1, %2" : "=v"(ru) : "v"(au), "v"(bu));
    return __builtin_bit_cast(h2, ru);
}

// One dispatch, three jobs (fp16 channel-pair packing):
//   blocks [0,841)    : zero-padded x -> fp16 pairs (ch 2cp, 2cp+1) at wsu+XOFFu
//   blocks [841,877)  : weights -> fp16 pairs at wsu+WOFFu, ordered
//                       [otile][wv][oo][cl][t] (R11 layout: contiguous 72-dword
//                       blocks per (otile,wv,oo) for batched s_load)
//   block  877        : mu = mean|w| (fp32) -> ws[0]
__global__ __launch_bounds__(256) void prep(const float* __restrict__ x,
                                            const float* __restrict__ w,
                                            float* __restrict__ ws) {
    unsigned* wsu = reinterpret_cast<unsigned*>(ws);
    if (blockIdx.x < XPKBLKS) {
        int idx = blockIdx.x * 256 + threadIdx.x;      // 0..NXPK-1
        int bc  = idx / PIMG;                          // b*16 + cp
        int r   = idx - bc * PIMG;
        int ph  = r / PW;
        int pw  = r - ph * PW;
        int hh  = ph - 1, wc = pw - 1;
        float v0 = 0.f, v1 = 0.f;
        if ((unsigned)hh < (unsigned)HH && (unsigned)wc < (unsigned)WW) {
            int base = ((bc >> 4) * CIN + (bc & 15) * 2) * IMG + hh * WW + wc;
            v0 = x[base];                              // channel 2cp   (coalesced)
            v1 = x[base + IMG];                        // channel 2cp+1
        }
        h2 p; p.x = (_Float16)v0; p.y = (_Float16)v1;
        wsu[XOFFu + idx] = __builtin_bit_cast(unsigned, p);
        return;
    }
    if (blockIdx.x < XPKBLKS + WPKBLKS) {
        int idx = (blockIdx.x - XPKBLKS) * 256 + threadIdx.x;  // 0..NWPK-1
        // decode [otile][wvq][oo][cl][t] ; strides 576/288/72/9/1
        int otile = idx / 576;
        int r     = idx - otile * 576;
        int wvq   = r / 288;
        int r2    = r - wvq * 288;
        int oo    = r2 / 72;
        int r3    = r2 - oo * 72;
        int cl    = r3 / 9;
        int t     = r3 - cl * 9;
        int o     = otile * OT + oo;
        int cp    = wvq * 8 + cl;
        int src   = o * (CIN * 9) + cp * 18 + t;
        h2 p; p.x = (_Float16)w[src]; p.y = (_Float16)w[src + 9];
        wsu[WOFFu + idx] = __builtin_bit_cast(unsigned, p);
        return;
    }
    // |w| mean (fp32 source) -> ws[0]
    float s = 0.f;
    const float4* w4 = reinterpret_cast<const float4*>(w);
    #pragma unroll
    for (int k = 0; k < 18; ++k) {
        float4 v = w4[k * 256 + threadIdx.x];
        s += fabsf(v.x) + fabsf(v.y) + fabsf(v.z) + fabsf(v.w);
    }
    #pragma unroll
    for (int off = 32; off; off >>= 1) s += __shfl_down(s, off);
    __shared__ float sm[4];
    if ((threadIdx.x & 63) == 0) sm[threadIdx.x >> 6] = s;
    __syncthreads();
    if (threadIdx.x == 0)
        ws[0] = (sm[0] + sm[1] + sm[2] + sm[3]) * (1.0f / (float)NW);
}

// R14 post-mortem: 5 structural rewrites all plateau at ~69-70us -> the bound
// is structure-invariant = the instruction stream. Theory: v_dot2_f32_f16 is
// SUB-RATE on gfx950 (never ubenched; assumed full-rate). Fix: accumulate each
// 9-tap group as a full-rate v_pk_add_f16 TREE (depth 4, good ILP), fold into
// fp32 with ONE fdot2 per (oo,cp): fdot2/wave 288 -> 32, same total instrs.
// Base = R11 (best, 68.6): SGPR 36-dword weight batches, xall hoist.
// R3 lesson: wave-uniform addressing via readfirstlane. R2: literal indices.
__global__ __launch_bounds__(128) void minconv_kernel(const float* __restrict__ ws,
                                                      const float* __restrict__ wts,
                                                      float* __restrict__ out) {
    const unsigned* wsu = reinterpret_cast<const unsigned*>(ws);
    const int lane = threadIdx.x & 63;
    const int wv   = threadIdx.x >> 6;
    const int wvs  = __builtin_amdgcn_readfirstlane(wv);   // SGPR copy
    const int hw = blockIdx.x * 64 + lane;             // 0..3135 exact
    const int o0 = blockIdx.y * OT;
    const int b  = blockIdx.z;
    const int h  = hw / WW;
    const int w  = hw - h * WW;

    const float mu = ws[0];                            // uniform s_load

    const int cp0 = wvs * 8;                           // this wave's channel-pairs
    const unsigned* xq = wsu + XOFFu + (size_t)(b * 16 + cp0) * PIMG + h * PW + w;
    const unsigned* wq0 = wsu + WOFFu + blockIdx.y * 576 + wvs * 288;  // scalar

    // ---- phase 1: issue ALL 72 tap loads (VMEM, pipelined) ----
    h2 xall[72];                                       // constant-indexed -> VGPRs
    #pragma unroll
    for (int cp = 0; cp < 8; ++cp)
        #pragma unroll
        for (int kh = 0; kh < 3; ++kh)
            #pragma unroll
            for (int kw = 0; kw < 3; ++kw)
                xall[cp * 9 + kh * 3 + kw] =
                    __builtin_bit_cast(h2, xq[cp * PIMG + kh * PW + kw]);

    // ---- phase 2: compute; per (oo,cl): 9 pkmin + 8-pkadd tree + 1 fdot2 ----
    h2 ones; ones.x = (_Float16)1.f; ones.y = (_Float16)1.f;
    float acc0 = 0.f, acc1 = 0.f, acc2 = 0.f, acc3 = 0.f;

    unsigned wA[36], wB[36];                           // uniform -> SGPR batches
    #pragma unroll
    for (int i = 0; i < 36; ++i) wA[i] = wq0[i];       // prefetch oo=0 half A

    #pragma unroll
    for (int oo = 0; oo < OT; ++oo) {
        #pragma unroll
        for (int i = 0; i < 36; ++i) wB[i] = wq0[oo * 72 + 36 + i];

        float a = 0.f;
        #pragma unroll
        for (int cl = 0; cl < 4; ++cl) {               // half A: cl 0..3
            h2 m[9];
            #pragma unroll
            for (int t = 0; t < 9; ++t)
                m[t] = pkmin_vs(xall[cl * 9 + t], wA[cl * 9 + t]);
            h2 t01 = pkadd(m[0], m[1]), t23 = pkadd(m[2], m[3]);
            h2 t45 = pkadd(m[4], m[5]), t67 = pkadd(m[6], m[7]);
            h2 q0 = pkadd(t01, t23), q1 = pkadd(t45, t67);
            h2 s9 = pkadd(pkadd(q0, q1), m[8]);
            a = __builtin_amdgcn_fdot2(s9, ones, a, false);    // 1 fdot2/group
        }

        if (oo < OT - 1) {
            #pragma unroll
            for (int i = 0; i < 36; ++i) wA[i] = wq0[(oo + 1) * 72 + i];
        }

        #pragma unroll
        for (int cl = 0; cl < 4; ++cl) {               // half B: cl 4..7
            h2 m[9];
            #pragma unroll
            for (int t = 0; t < 9; ++t)
                m[t] = pkmin_vs(xall[(cl + 4) * 9 + t], wB[cl * 9 + t]);
            h2 t01 = pkadd(m[0], m[1]), t23 = pkadd(m[2], m[3]);
            h2 t45 = pkadd(m[4], m[5]), t67 = pkadd(m[6], m[7]);
            h2 q0 = pkadd(t01, t23), q1 = pkadd(t45, t67);
            h2 s9 = pkadd(pkadd(q0, q1), m[8]);
            a = __builtin_amdgcn_fdot2(s9, ones, a, false);
        }

        switch (oo) {                                  // literal acc names only
            case 0: acc0 = a; break;
            case 1: acc1 = a; break;
            case 2: acc2 = a; break;
            case 3: acc3 = a; break;
        }
    }

    // cross-wave combine: wave0 keeps oo 0,1; wave1 keeps oo 2,3.
    __shared__ float red[2][2][64];                    // 1 KiB
    if (wv == 0) {
        red[0][0][lane] = acc2;
        red[0][1][lane] = acc3;
    } else {
        red[1][0][lane] = acc0;
        red[1][1][lane] = acc1;
    }
    __syncthreads();

    float* ob = out + ((size_t)b * OCH + o0) * IMG + hw;
    if (wv == 0) {
        ob[0]       = mu * (acc0 + red[1][0][lane]);
        ob[IMG]     = mu * (acc1 + red[1][1][lane]);
    } else {
        ob[2 * IMG] = mu * (acc2 + red[0][0][lane]);
        ob[3 * IMG] = mu * (acc3 + red[0][1][lane]);
    }
}

extern "C" void kernel_launch(void* const* d_in, const int* in_sizes, int n_in,
                              void* d_out, int out_size, void* d_ws, size_t ws_size,
                              hipStream_t stream) {
    const float* x   = (const float*)d_in[0];   // 4*32*56*56
    const float* w   = (const float*)d_in[1];   // 64*32*3*3
    float*       out = (float*)d_out;           // 4*64*56*56
    float*       ws  = (float*)d_ws;

    prep<<<XPKBLKS + WPKBLKS + 1, 256, 0, stream>>>(x, w, ws);
    dim3 grid(IMG / 64, OCH / OT, BB);          // 49 x 16 x 4 = 3136 blocks
    minconv_kernel<<<grid, 128, 0, stream>>>(ws, w, out);
}

// Round 16
// 67.789 us; speedup vs baseline: 1.0333x; 1.0071x over previous
//
#include <hip/hip_runtime.h>

#define CIN  32
#define OCH  64
#define HH   56
#define WW   56
#define BB   4
#define OT   4                  // output channels per block
#define IMG  (HH * WW)          // 3136
#define NW   18432              // 64*32*3*3
#define PH   58
#define PW   58
#define PIMG (PH * PW)          // 3364 padded image
#define NXPK (BB * (CIN/2) * PIMG)   // 215296 packed x uints
#define XPKBLKS (NXPK / 256)         // 841 (exact)
#define NWPK (OCH * (CIN/2) * 9)     // 9216 packed weight uints
#define WPKBLKS (NWPK / 256)         // 36 (exact)
#define WOFFu 64                     // packed weights at wsu+64 (uint units)
#define XOFFu (WOFFu + NWPK)         // 9280: packed x follows (256B aligned)

typedef _Float16 h2 __attribute__((ext_vector_type(2)));

// v_pk_min_f16, both operands VGPR (weights come from LDS uint4).
static __device__ __forceinline__ h2 pkmin_vv(h2 xv, unsigned wu) {
    unsigned xu = __builtin_bit_cast(unsigned, xv);
    unsigned ru;
    asm("v_pk_min_f16 %0, %1, %2" : "=v"(ru) : "v"(xu), "v"(wu));
    return __builtin_bit_cast(h2, ru);
}

// One dispatch, three jobs (fp16 channel-pair packing):
//   blocks [0,841)    : zero-padded x -> fp16 pairs (ch 2cp, 2cp+1) at wsu+XOFFu
//   blocks [841,877)  : weights -> fp16 pairs at wsu+WOFFu, ordered
//                       [otile][wv4][cl][t][oo]: one ds_read_b128 in minconv
//                       delivers tap t of channel-pair (wv4*4+cl) for ALL 4 oo.
//   block  877        : mu = mean|w| (fp32) -> ws[0]
__global__ __launch_bounds__(256) void prep(const float* __restrict__ x,
                                            const float* __restrict__ w,
                                            float* __restrict__ ws) {
    unsigned* wsu = reinterpret_cast<unsigned*>(ws);
    if (blockIdx.x < XPKBLKS) {
        int idx = blockIdx.x * 256 + threadIdx.x;      // 0..NXPK-1
        int bc  = idx / PIMG;                          // b*16 + cp
        int r   = idx - bc * PIMG;
        int ph  = r / PW;
        int pw  = r - ph * PW;
        int hh  = ph - 1, wc = pw - 1;
        float v0 = 0.f, v1 = 0.f;
        if ((unsigned)hh < (unsigned)HH && (unsigned)wc < (unsigned)WW) {
            int base = ((bc >> 4) * CIN + (bc & 15) * 2) * IMG + hh * WW + wc;
            v0 = x[base];                              // channel 2cp   (coalesced)
            v1 = x[base + IMG];                        // channel 2cp+1
        }
        h2 p; p.x = (_Float16)v0; p.y = (_Float16)v1;
        wsu[XOFFu + idx] = __builtin_bit_cast(unsigned, p);
        return;
    }
    if (blockIdx.x < XPKBLKS + WPKBLKS) {
        int idx = (blockIdx.x - XPKBLKS) * 256 + threadIdx.x;  // 0..NWPK-1
        // decode [otile][wv4][cl][t][oo] ; strides 576/144/36/4/1
        int otile = idx / 576;
        int r     = idx - otile * 576;
        int wv4   = r / 144;
        int r2    = r - wv4 * 144;
        int cl    = r2 / 36;
        int r3    = r2 - cl * 36;
        int t     = r3 >> 2;
        int oo    = r3 & 3;
        int o     = otile * OT + oo;
        int cp    = wv4 * 4 + cl;
        int src   = o * (CIN * 9) + cp * 18 + t;
        h2 p; p.x = (_Float16)w[src]; p.y = (_Float16)w[src + 9];
        wsu[WOFFu + idx] = __builtin_bit_cast(unsigned, p);
        return;
    }
    // |w| mean (fp32 source) -> ws[0]
    float s = 0.f;
    const float4* w4 = reinterpret_cast<const float4*>(w);
    #pragma unroll
    for (int k = 0; k < 18; ++k) {
        float4 v = w4[k * 256 + threadIdx.x];
        s += fabsf(v.x) + fabsf(v.y) + fabsf(v.z) + fabsf(v.w);
    }
    #pragma unroll
    for (int off = 32; off; off >>= 1) s += __shfl_down(s, off);
    __shared__ float sm[4];
    if ((threadIdx.x & 63) == 0) sm[threadIdx.x >> 6] = s;
    __syncthreads();
    if (threadIdx.x == 0)
        ws[0] = (sm[0] + sm[1] + sm[2] + sm[3]) * (1.0f / (float)NW);
}

// R15 post-mortem: 7 variants plateau at minconv ~19-21us vs ~3.3us issue
// floor -> ~6100 cyc/wave of stall, structure-invariant. Untested axis: TLP
// (all fp16 variants ran ~2.5 waves/SIMD). R16: split channels 4-ways --
// block=256 = 4 waves x 4cp each -> 12544 waves (~8/SIMD resident), totals
// (loads, math) byte-identical to R12/R15. If the stall is latency-type,
// TLP hides it; if null, it's shared-unit serialization -> ceiling.
// R3 lesson: readfirstlane wave-uniform values used in addressing.
// R2 lesson: literal register-array indices everywhere (LDS/global may be
// runtime-indexed -- they're memory).
__global__ __launch_bounds__(256) void minconv_kernel(const float* __restrict__ ws,
                                                      const float* __restrict__ wts,
                                                      float* __restrict__ out) {
    const unsigned* wsu = reinterpret_cast<const unsigned*>(ws);
    const int tid  = threadIdx.x;
    const int lane = tid & 63;
    const int wv   = tid >> 6;                         // 0..3: channel quarter
    const int wvs  = __builtin_amdgcn_readfirstlane(wv);   // SGPR copy
    const int hw = blockIdx.x * 64 + lane;             // 0..3135 exact
    const int o0 = blockIdx.y * OT;
    const int b  = blockIdx.z;
    const int h  = hw / WW;
    const int w  = hw - h * WW;

    const float mu = ws[0];                            // uniform s_load

    __shared__ __align__(16) unsigned wlds[576];       // o-tile weights [wv4][cl][t][oo]
    __shared__ float red[4][4][64];                    // [src_wave][oo][lane], 4 KiB

    // ---- stage weights: 576 contiguous dwords, 256 threads ----
    {
        const unsigned* wt = wsu + WOFFu + blockIdx.y * 576;
        *reinterpret_cast<uint2*>(&wlds[tid * 2]) =
            *reinterpret_cast<const uint2*>(&wt[tid * 2]);     // 512 dwords
        if (tid < 64) wlds[512 + tid] = wt[512 + tid];         // remaining 64
    }

    const int cp0 = wvs * 4;                           // this wave's channel-pairs
    const unsigned* xq = wsu + XOFFu + (size_t)(b * 16 + cp0) * PIMG + h * PW + w;

    __syncthreads();                                   // weights staged

    // ---- main loop: per cl, 9 x-taps then 9 broadcast b128 weight reads ----
    h2 ones; ones.x = (_Float16)1.f; ones.y = (_Float16)1.f;
    float a0 = 0.f, a1 = 0.f, a2 = 0.f, a3 = 0.f;      // oo 0..3, this cp-quarter
    const unsigned* wl = wlds + wv * 144;              // per-wave LDS base

    #pragma unroll
    for (int cl = 0; cl < 4; ++cl) {
        h2 xv[9];                                      // literal indices only
        #pragma unroll
        for (int kh = 0; kh < 3; ++kh)
            #pragma unroll
            for (int kw = 0; kw < 3; ++kw)
                xv[kh * 3 + kw] =
                    __builtin_bit_cast(h2, xq[cl * PIMG + kh * PW + kw]);
        #pragma unroll
        for (int t = 0; t < 9; ++t) {
            uint4 q = *reinterpret_cast<const uint4*>(&wl[cl * 36 + t * 4]);
            h2 m0 = pkmin_vv(xv[t], q.x);
            a0 = __builtin_amdgcn_fdot2(m0, ones, a0, false);
            h2 m1 = pkmin_vv(xv[t], q.y);
            a1 = __builtin_amdgcn_fdot2(m1, ones, a1, false);
            h2 m2 = pkmin_vv(xv[t], q.z);
            a2 = __builtin_amdgcn_fdot2(m2, ones, a2, false);
            h2 m3 = pkmin_vv(xv[t], q.w);
            a3 = __builtin_amdgcn_fdot2(m3, ones, a3, false);
        }
    }

    // ---- 4-way cross-wave reduce: wave wv owns output channel o0+wv ----
    red[wv][0][lane] = a0;                             // LDS addr may be runtime
    red[wv][1][lane] = a1;
    red[wv][2][lane] = a2;
    red[wv][3][lane] = a3;
    __syncthreads();

    float s = red[0][wv][lane] + red[1][wv][lane]
            + red[2][wv][lane] + red[3][wv][lane];
    out[((size_t)b * OCH + o0 + wv) * IMG + hw] = mu * s;
}

extern "C" void kernel_launch(void* const* d_in, const int* in_sizes, int n_in,
                              void* d_out, int out_size, void* d_ws, size_t ws_size,
                              hipStream_t stream) {
    const float* x   = (const float*)d_in[0];   // 4*32*56*56
    const float* w   = (const float*)d_in[1];   // 64*32*3*3
    float*       out = (float*)d_out;           // 4*64*56*56
    float*       ws  = (float*)d_ws;

    prep<<<XPKBLKS + WPKBLKS + 1, 256, 0, stream>>>(x, w, ws);
    dim3 grid(IMG / 64, OCH / OT, BB);          // 49 x 16 x 4 = 3136 blocks
    minconv_kernel<<<grid, 256, 0, stream>>>(ws, w, out);
}

// Round 17
// 67.125 us; speedup vs baseline: 1.0435x; 1.0099x over previous
//
#include <hip/hip_runtime.h>

#define CIN  32
#define OCH  64
#define HH   56
#define WW   56
#define BB   4
#define OT   4                  // output channels per block
#define IMG  (HH * WW)          // 3136
#define NW   18432              // 64*32*3*3
#define PH   58
#define PW   58
#define PIMG (PH * PW)          // 3364 padded image
#define XP4  (BB * 4 * PIMG)    // 53824 uint4 x-entries: [b][oct][pixel] -> 8 ch
#define XP4BLKS ((XP4 + 255) / 256)  // 211 (tail-guarded)
#define NWPK (OCH * (CIN/2) * 9)     // 9216 packed weight dwords
#define WPKBLKS (NWPK / 256)         // 36 (exact)
#define WOFFu 64                     // packed weights at wsu+64 (dword units)
#define XOFFu (WOFFu + NWPK)         // 9280 dwords = 16B-aligned; x-uint4s follow

typedef _Float16 h2 __attribute__((ext_vector_type(2)));

// v_pk_min_f16, both operands VGPR (x from global uint4, w from LDS uint4).
static __device__ __forceinline__ h2 pkmin_vv(h2 xv, unsigned wu) {
    unsigned xu = __builtin_bit_cast(unsigned, xv);
    unsigned ru;
    asm("v_pk_min_f16 %0, %1, %2" : "=v"(ru) : "v"(xu), "v"(wu));
    return __builtin_bit_cast(h2, ru);
}
static __device__ __forceinline__ h2 ld_h2(unsigned u) {
    return __builtin_bit_cast(h2, u);
}

// One dispatch, three jobs:
//   blocks [0,211)    : zero-padded x -> uint4 entries [b][oct][pixel] holding
//                       8 fp16 channels (pairs oct*8+{0,1},{2,3},{4,5},{6,7})
//   blocks [211,247)  : weights -> fp16 pairs at wsu+WOFFu, layout
//                       [otile][oct][t][q][oo] (dword strides 576/144/16/4/1):
//                       one ds_read_b128 = tap t, pair q, ALL 4 oo.
//   block  247        : mu = mean|w| (fp32) -> ws[0]
__global__ __launch_bounds__(256) void prep(const float* __restrict__ x,
                                            const float* __restrict__ w,
                                            float* __restrict__ ws) {
    unsigned* wsu = reinterpret_cast<unsigned*>(ws);
    if (blockIdx.x < XP4BLKS) {
        int idx = blockIdx.x * 256 + threadIdx.x;      // 0..XP4-1 (guarded)
        if (idx < XP4) {
            int boct = idx / PIMG;                     // b*4 + oct
            int pix  = idx - boct * PIMG;
            int ph   = pix / PW;
            int pw   = pix - ph * PW;
            int hh   = ph - 1, wc = pw - 1;
            int b    = boct >> 2, oct = boct & 3;
            uint4 val = make_uint4(0u, 0u, 0u, 0u);
            if ((unsigned)hh < (unsigned)HH && (unsigned)wc < (unsigned)WW) {
                int src = (b * CIN + oct * 8) * IMG + hh * WW + wc;
                unsigned* vp = &val.x;
                #pragma unroll
                for (int q = 0; q < 4; ++q) {
                    h2 p;
                    p.x = (_Float16)x[src + (2 * q) * IMG];
                    p.y = (_Float16)x[src + (2 * q + 1) * IMG];
                    vp[q] = __builtin_bit_cast(unsigned, p);
                }
            }
            reinterpret_cast<uint4*>(wsu + XOFFu)[idx] = val;
        }
        return;
    }
    if (blockIdx.x < XP4BLKS + WPKBLKS) {
        int idx = (blockIdx.x - XP4BLKS) * 256 + threadIdx.x;  // 0..NWPK-1
        // decode [otile][oct][t][q][oo]; strides 576/144/16/4/1
        int otile = idx / 576;
        int r     = idx - otile * 576;
        int oct   = r / 144;
        int r2    = r - oct * 144;
        int t     = r2 / 16;
        int r3    = r2 - t * 16;
        int q     = r3 >> 2;
        int oo    = r3 & 3;
        int o     = otile * OT + oo;
        int cp    = oct * 4 + q;                       // ch pair -> ch 2cp,2cp+1
        int src   = o * (CIN * 9) + cp * 18 + t;
        h2 p; p.x = (_Float16)w[src]; p.y = (_Float16)w[src + 9];
        wsu[WOFFu + idx] = __builtin_bit_cast(unsigned, p);
        return;
    }
    // |w| mean (fp32 source) -> ws[0]
    float s = 0.f;
    const float4* w4 = reinterpret_cast<const float4*>(w);
    #pragma unroll
    for (int k = 0; k < 18; ++k) {
        float4 v = w4[k * 256 + threadIdx.x];
        s += fabsf(v.x) + fabsf(v.y) + fabsf(v.z) + fabsf(v.w);
    }
    #pragma unroll
    for (int off = 32; off; off >>= 1) s += __shfl_down(s, off);
    __shared__ float sm[4];
    if ((threadIdx.x & 63) == 0) sm[threadIdx.x >> 6] = s;
    __syncthreads();
    if (threadIdx.x == 0)
        ws[0] = (sm[0] + sm[1] + sm[2] + sm[3]) * (1.0f / (float)NW);
}

// R16 post-mortem: TLP(8 waves/SIMD) null -> shared-unit serialization. The
// cross-variant invariant is ~451k per-lane 4B x-load VMEM instrs (1764/CU
// through the one TA/L1 pipe ~ 10us). R17: x packed as uint4 (8ch/16B) ->
// ONE dwordx4 per tap per wave = 9 VMEM/wave (4x fewer instrs, same bytes,
// 1KB/wave-op coalescing sweet spot). Weights: 4 broadcast ds_read_b128/tap.
// Math unchanged: 288 VALU/wave, 8 fdot2 chains.
// R3 lesson: readfirstlane wave-uniform addressing. R2: literal reg indices.
__global__ __launch_bounds__(256) void minconv_kernel(const float* __restrict__ ws,
                                                      const float* __restrict__ wts,
                                                      float* __restrict__ out) {
    const unsigned* wsu = reinterpret_cast<const unsigned*>(ws);
    const int tid  = threadIdx.x;
    const int lane = tid & 63;
    const int wv   = tid >> 6;                         // 0..3: channel oct
    const int wvs  = __builtin_amdgcn_readfirstlane(wv);   // SGPR copy
    const int hw = blockIdx.x * 64 + lane;             // 0..3135 exact
    const int o0 = blockIdx.y * OT;
    const int b  = blockIdx.z;
    const int h  = hw / WW;
    const int w  = hw - h * WW;

    const float mu = ws[0];                            // uniform s_load

    __shared__ __align__(16) unsigned wlds[576];       // [oct][t][q][oo]
    __shared__ float red[4][4][64];                    // [src_wave][oo][lane]

    // ---- stage weights: 576 contiguous dwords ----
    {
        const unsigned* wt = wsu + WOFFu + blockIdx.y * 576;
        *reinterpret_cast<uint2*>(&wlds[tid * 2]) =
            *reinterpret_cast<const uint2*>(&wt[tid * 2]);     // 512 dwords
        if (tid < 64) wlds[512 + tid] = wt[512 + tid];         // remaining 64
    }

    // x base: this wave's oct, this lane's pixel (uint4 entries)
    const uint4* xq4 = reinterpret_cast<const uint4*>(wsu + XOFFu)
                     + (size_t)(b * 4 + wvs) * PIMG + h * PW + w;

    __syncthreads();                                   // weights staged

    // ---- main loop: 9 taps x {1 dwordx4 + 4 b128 + 16 pkmin + 16 fdot2} ----
    h2 ones; ones.x = (_Float16)1.f; ones.y = (_Float16)1.f;
    float a0e = 0.f, a1e = 0.f, a2e = 0.f, a3e = 0.f;  // even-q chains
    float a0o = 0.f, a1o = 0.f, a2o = 0.f, a3o = 0.f;  // odd-q chains
    const unsigned* wl = wlds + wv * 144;              // per-wave LDS base

    #pragma unroll
    for (int kh = 0; kh < 3; ++kh) {
        #pragma unroll
        for (int kw = 0; kw < 3; ++kw) {
            const int t = kh * 3 + kw;
            uint4 xt = xq4[kh * PW + kw];              // 8 channels, 1 VMEM
            h2 x0 = ld_h2(xt.x), x1 = ld_h2(xt.y);
            h2 x2 = ld_h2(xt.z), x3 = ld_h2(xt.w);
            uint4 w0 = *reinterpret_cast<const uint4*>(&wl[t * 16 + 0]);
            uint4 w1 = *reinterpret_cast<const uint4*>(&wl[t * 16 + 4]);
            uint4 w2 = *reinterpret_cast<const uint4*>(&wl[t * 16 + 8]);
            uint4 w3 = *reinterpret_cast<const uint4*>(&wl[t * 16 + 12]);
            a0e = __builtin_amdgcn_fdot2(pkmin_vv(x0, w0.x), ones, a0e, false);
            a1e = __builtin_amdgcn_fdot2(pkmin_vv(x0, w0.y), ones, a1e, false);
            a2e = __builtin_amdgcn_fdot2(pkmin_vv(x0, w0.z), ones, a2e, false);
            a3e = __builtin_amdgcn_fdot2(pkmin_vv(x0, w0.w), ones, a3e, false);
            a0o = __builtin_amdgcn_fdot2(pkmin_vv(x1, w1.x), ones, a0o, false);
            a1o = __builtin_amdgcn_fdot2(pkmin_vv(x1, w1.y), ones, a1o, false);
            a2o = __builtin_amdgcn_fdot2(pkmin_vv(x1, w1.z), ones, a2o, false);
            a3o = __builtin_amdgcn_fdot2(pkmin_vv(x1, w1.w), ones, a3o, false);
            a0e = __builtin_amdgcn_fdot2(pkmin_vv(x2, w2.x), ones, a0e, false);
            a1e = __builtin_amdgcn_fdot2(pkmin_vv(x2, w2.y), ones, a1e, false);
            a2e = __builtin_amdgcn_fdot2(pkmin_vv(x2, w2.z), ones, a2e, false);
            a3e = __builtin_amdgcn_fdot2(pkmin_vv(x2, w2.w), ones, a3e, false);
            a0o = __builtin_amdgcn_fdot2(pkmin_vv(x3, w3.x), ones, a0o, false);
            a1o = __builtin_amdgcn_fdot2(pkmin_vv(x3, w3.y), ones, a1o, false);
            a2o = __builtin_amdgcn_fdot2(pkmin_vv(x3, w3.z), ones, a2o, false);
            a3o = __builtin_amdgcn_fdot2(pkmin_vv(x3, w3.w), ones, a3o, false);
        }
    }

    // ---- 4-way cross-wave reduce: wave wv owns output channel o0+wv ----
    red[wv][0][lane] = a0e + a0o;
    red[wv][1][lane] = a1e + a1o;
    red[wv][2][lane] = a2e + a2o;
    red[wv][3][lane] = a3e + a3o;
    __syncthreads();

    float s = red[0][wv][lane] + red[1][wv][lane]
            + red[2][wv][lane] + red[3][wv][lane];
    out[((size_t)b * OCH + o0 + wv) * IMG + hw] = mu * s;
}

extern "C" void kernel_launch(void* const* d_in, const int* in_sizes, int n_in,
                              void* d_out, int out_size, void* d_ws, size_t ws_size,
                              hipStream_t stream) {
    const float* x   = (const float*)d_in[0];   // 4*32*56*56
    const float* w   = (const float*)d_in[1];   // 64*32*3*3
    float*       out = (float*)d_out;           // 4*64*56*56
    float*       ws  = (float*)d_ws;

    prep<<<XP4BLKS + WPKBLKS + 1, 256, 0, stream>>>(x, w, ws);
    dim3 grid(IMG / 64, OCH / OT, BB);          // 49 x 16 x 4 = 3136 blocks
    minconv_kernel<<<grid, 256, 0, stream>>>(ws, w, out);
}